// Round 1
// baseline (535.121 us; speedup 1.0000x reference)
//
#include <hip/hip_runtime.h>

typedef unsigned short u16;
typedef __attribute__((ext_vector_type(8))) __bf16 bf16x8;
typedef __attribute__((ext_vector_type(4))) float f32x4;

__device__ __forceinline__ float bf2f(u16 u) {
  union { unsigned int i; float f; } v; v.i = ((unsigned int)u) << 16; return v.f;
}
__device__ __forceinline__ u16 f2bf(float f) {
  union { float f; unsigned int i; } v; v.f = f;
  unsigned int u = v.i;
  return (u16)((u + 0x7fffu + ((u >> 16) & 1u)) >> 16);  // RNE
}
__device__ __forceinline__ void async16(void* lds, const void* g) {
  __builtin_amdgcn_global_load_lds(
      (const __attribute__((address_space(1))) unsigned int*)g,
      (__attribute__((address_space(3))) unsigned int*)lds, 16, 0, 0);
}

// ---------------- conversions ----------------
__global__ void k_convert_x(const float* __restrict__ x, u16* __restrict__ xb) {
  int idx = blockIdx.x * 256 + threadIdx.x;       // 65536*512 threads
  int m = idx >> 9, c = idx & 511;
  float v = (c < 500) ? x[(size_t)m * 500 + c] : 0.f;
  xb[idx] = f2bf(v);
}

__global__ void k_convert_w(const float* __restrict__ Wq, const float* __restrict__ Wk,
                            const float* __restrict__ Wv, u16* __restrict__ Wt) {
  int idx = blockIdx.x * 256 + threadIdx.x;       // 3*512*512
  int g = idx >> 18;
  int r = idx & 262143;
  int n = r >> 9, k = r & 511;
  const float* W = (g == 0) ? Wq : (g == 1) ? Wk : Wv;
  float v = (n < 500 && k < 500) ? W[(size_t)k * 500 + n] : 0.f;   // transpose
  Wt[idx] = f2bf(v);
}

__global__ void k_tables(float* __restrict__ cos_t, float* __restrict__ sin_t) {
  int t = blockIdx.x, i = threadIdx.x;
  float c = 0.f, s = 0.f;
  if (i < 250) {
    float ex = (2.0f * (float)(i >> 1)) / 500.0f;
    float fr = powf(1e-4f, ex);
    float ang = (float)t * fr;
    c = cosf(ang); s = sinf(ang);
  }
  cos_t[t * 256 + i] = c;
  sin_t[t * 256 + i] = s;
}

// ---------------- QKV projection GEMM ----------------
// C[m][n] = sum_k xb[m][k] * Wt[n][k]   (Wt is W^T, padded)
__global__ __launch_bounds__(256) void k_gemm_qkv(
    const u16* __restrict__ xb, const u16* __restrict__ Wt,
    u16* __restrict__ qb, u16* __restrict__ kb, u16* __restrict__ vT) {
  __shared__ u16 As[128][32];   // 8KB
  __shared__ u16 Bs[128][32];   // 8KB
  const int tid = threadIdx.x;
  const int lane = tid & 63;
  const int w = tid >> 6;
  const int wm = (w >> 1) * 64, wn = (w & 1) * 64;
  const int bm = blockIdx.x * 128;
  const int bn = blockIdx.y * 128;
  const int g = blockIdx.z;
  const int lrow = lane & 15, lhi = lane >> 4;

  const u16* Ab = xb + (size_t)bm * 512;
  const u16* Bb = Wt + ((size_t)(g * 512 + bn)) * 512;

  f32x4 acc[4][4] = {};

  for (int k0 = 0; k0 < 512; k0 += 32) {
    __syncthreads();
#pragma unroll
    for (int it = 0; it < 2; ++it) {
      int gi = it * 256 + tid;          // 16B chunk id; LDS off = gi*16
      int row = gi >> 2;
      int cp = (gi & 3) * 8;
      async16(&As[row][cp], Ab + (size_t)row * 512 + k0 + cp);
      async16(&Bs[row][cp], Bb + (size_t)row * 512 + k0 + cp);
    }
    __syncthreads();
    bf16x8 a[4], b[4];
#pragma unroll
    for (int mi = 0; mi < 4; ++mi)
      a[mi] = *(const bf16x8*)&As[wm + mi * 16 + lrow][lhi * 8];
#pragma unroll
    for (int ni = 0; ni < 4; ++ni)
      b[ni] = *(const bf16x8*)&Bs[wn + ni * 16 + lrow][lhi * 8];
#pragma unroll
    for (int mi = 0; mi < 4; ++mi)
#pragma unroll
      for (int ni = 0; ni < 4; ++ni)
        acc[mi][ni] = __builtin_amdgcn_mfma_f32_16x16x32_bf16(a[mi], b[ni], acc[mi][ni], 0, 0, 0);
  }

#pragma unroll
  for (int mi = 0; mi < 4; ++mi)
#pragma unroll
    for (int ni = 0; ni < 4; ++ni)
#pragma unroll
      for (int j = 0; j < 4; ++j) {
        int m = bm + wm + mi * 16 + lhi * 4 + j;       // C/D: row=(l>>4)*4+j
        int n = bn + wn + ni * 16 + lrow;              //      col=l&15
        u16 h = f2bf(acc[mi][ni][j]);
        if (g == 0)      qb[(size_t)m * 512 + n] = h;
        else if (g == 1) kb[(size_t)m * 512 + n] = h;
        else             vT[(size_t)(m >> 8) * 131072 + (size_t)n * 256 + (m & 255)] = h;
      }
}

// ---------------- RoPE (in place on q,k) ----------------
__global__ void k_rope(u16* __restrict__ qb, u16* __restrict__ kb,
                       const float* __restrict__ cos_t, const float* __restrict__ sin_t) {
  int m = blockIdx.x;
  int i = threadIdx.x;
  if (i >= 250) return;
  int t = m & 255;
  float c = cos_t[t * 256 + i], s = sin_t[t * 256 + i];
  size_t base = (size_t)m * 512;
  float q1 = bf2f(qb[base + i]), q2 = bf2f(qb[base + 250 + i]);
  qb[base + i]       = f2bf(q1 * c - q2 * s);
  qb[base + 250 + i] = f2bf(q1 * s + q2 * c);
  float k1 = bf2f(kb[base + i]), k2 = bf2f(kb[base + 250 + i]);
  kb[base + i]       = f2bf(k1 * c - k2 * s);
  kb[base + 250 + i] = f2bf(k1 * s + k2 * c);
}

// ---------------- fused causal attention ----------------
// block = (q-tile of 64 rows, batch). 4 waves x 16 rows.
__global__ __launch_bounds__(256) void k_attn(
    const u16* __restrict__ qb, const u16* __restrict__ kb,
    const u16* __restrict__ vT, float* __restrict__ out) {
  __shared__ u16 smem[32768];          // 64 KB
  u16* Ks = smem;                      // [32][512]  (phase A)
  u16* Ps = smem + 16384;              // [64][256]
  u16* Vs = smem;                      // [512][32]  (phase B, aliases Ks)

  const int tid = threadIdx.x;
  const int lane = tid & 63;
  const int w = tid >> 6;
  const int t0 = blockIdx.x * 64;
  const int b = blockIdx.y;
  const int smax = t0 + 63;
  const int lrow = lane & 15, lhi = lane >> 4;

  // Q fragments held in registers: 16 rows/wave, K=512 -> 16 frags
  const u16* qrow = qb + ((size_t)(b * 256 + t0 + w * 16 + lrow)) * 512;
  bf16x8 qf[16];
#pragma unroll
  for (int kk = 0; kk < 16; ++kk)
    qf[kk] = *(const bf16x8*)(qrow + kk * 32 + lhi * 8);

  // ---- phase A: S = Q K^T (64 x 256), causal tile skip ----
  f32x4 sa[16] = {};
#pragma unroll
  for (int st = 0; st < 8; ++st) {
    const int s0 = st * 32;
    if (s0 <= smax) {
      __syncthreads();
#pragma unroll
      for (int it = 0; it < 8; ++it) {
        int gi = it * 256 + tid;
        int row = gi >> 6;
        int cp = (gi & 63) * 8;
        async16(Ks + (size_t)gi * 8, kb + ((size_t)(b * 256 + s0 + row)) * 512 + cp);
      }
      __syncthreads();
#pragma unroll
      for (int ni = 0; ni < 2; ++ni)
#pragma unroll
        for (int kk = 0; kk < 16; ++kk) {
          bf16x8 bf = *(const bf16x8*)&Ks[(ni * 16 + lrow) * 512 + kk * 32 + lhi * 8];
          sa[st * 2 + ni] =
              __builtin_amdgcn_mfma_f32_16x16x32_bf16(qf[kk], bf, sa[st * 2 + ni], 0, 0, 0);
        }
    }
  }

  // ---- softmax (rows spread over 16 lanes sharing lane>>4) ----
  const float scale = 0.04472135954999579f;   // 500^-0.5
  float rmax[4] = {-1e30f, -1e30f, -1e30f, -1e30f};
#pragma unroll
  for (int n = 0; n < 16; ++n) {
    int s = n * 16 + lrow;
#pragma unroll
    for (int j = 0; j < 4; ++j) {
      int t = t0 + w * 16 + lhi * 4 + j;
      float v = sa[n][j] * scale;
      if (s > t) v = -1e30f;
      sa[n][j] = v;
      rmax[j] = fmaxf(rmax[j], v);
    }
  }
#pragma unroll
  for (int j = 0; j < 4; ++j)
#pragma unroll
    for (int msk = 1; msk < 16; msk <<= 1)
      rmax[j] = fmaxf(rmax[j], __shfl_xor(rmax[j], msk, 64));
  float rsum[4] = {0.f, 0.f, 0.f, 0.f};
#pragma unroll
  for (int n = 0; n < 16; ++n)
#pragma unroll
    for (int j = 0; j < 4; ++j) {
      float p = __expf(sa[n][j] - rmax[j]);
      sa[n][j] = p;
      rsum[j] += p;
    }
#pragma unroll
  for (int j = 0; j < 4; ++j)
#pragma unroll
    for (int msk = 1; msk < 16; msk <<= 1)
      rsum[j] += __shfl_xor(rsum[j], msk, 64);
  float rinv[4];
#pragma unroll
  for (int j = 0; j < 4; ++j) rinv[j] = 1.0f / rsum[j];

  // write P (bf16) to LDS; wave writes/reads only its own 16 rows
#pragma unroll
  for (int n = 0; n < 16; ++n)
#pragma unroll
    for (int j = 0; j < 4; ++j) {
      int s = n * 16 + lrow;
      int trow = w * 16 + lhi * 4 + j;
      Ps[trow * 256 + s] = f2bf(sa[n][j] * rinv[j]);
    }

  // ---- phase B: O = P V  (V tiles [512][32] staged in LDS) ----
  f32x4 o[32] = {};
#pragma unroll
  for (int st = 0; st < 8; ++st) {
    const int s0 = st * 32;
    if (s0 <= smax) {
      __syncthreads();
#pragma unroll
      for (int it = 0; it < 8; ++it) {
        int gi = it * 256 + tid;
        int h = gi >> 2;
        int sp = (gi & 3) * 8;
        async16(Vs + (size_t)gi * 8, vT + (size_t)b * 131072 + (size_t)h * 256 + s0 + sp);
      }
      __syncthreads();
      bf16x8 pf = *(const bf16x8*)&Ps[(w * 16 + lrow) * 256 + s0 + lhi * 8];
#pragma unroll
      for (int ni = 0; ni < 32; ++ni) {
        bf16x8 vf = *(const bf16x8*)&Vs[(ni * 16 + lrow) * 32 + lhi * 8];
        o[ni] = __builtin_amdgcn_mfma_f32_16x16x32_bf16(pf, vf, o[ni], 0, 0, 0);
      }
    }
  }

  // ---- epilogue ----
  const int tb = t0 + w * 16;
#pragma unroll
  for (int ni = 0; ni < 32; ++ni) {
    int h = ni * 16 + lrow;
    if (h < 500) {
#pragma unroll
      for (int j = 0; j < 4; ++j) {
        int t = tb + lhi * 4 + j;
        out[((size_t)(b * 256 + t)) * 500 + h] = o[ni][j];
      }
    }
  }
}

extern "C" void kernel_launch(void* const* d_in, const int* in_sizes, int n_in,
                              void* d_out, int out_size, void* d_ws, size_t ws_size,
                              hipStream_t stream) {
  const float* x  = (const float*)d_in[0];
  const float* Wq = (const float*)d_in[1];
  const float* Wk = (const float*)d_in[2];
  const float* Wv = (const float*)d_in[3];
  float* out = (float*)d_out;

  u16* xb = (u16*)d_ws;                 // [65536][512] bf16
  u16* qb = xb + 33554432;              // [65536][512]
  u16* kb = qb + 33554432;              // [65536][512]
  u16* vT = kb + 33554432;              // [256][512][256]
  u16* Wt = vT + 33554432;              // [1536][512]
  float* cos_t = (float*)(Wt + 786432); // [256][256]
  float* sin_t = cos_t + 65536;         // [256][256]

  k_convert_x<<<131072, 256, 0, stream>>>(x, xb);
  k_convert_w<<<3072, 256, 0, stream>>>(Wq, Wk, Wv, Wt);
  k_tables<<<256, 256, 0, stream>>>(cos_t, sin_t);
  k_gemm_qkv<<<dim3(512, 4, 3), 256, 0, stream>>>(xb, Wt, qb, kb, vT);
  k_rope<<<65536, 256, 0, stream>>>(qb, kb, cos_t, sin_t);
  k_attn<<<dim3(4, 256), 256, 0, stream>>>(qb, kb, vT, out);
}

// Round 2
// 481.704 us; speedup vs baseline: 1.1109x; 1.1109x over previous
//
#include <hip/hip_runtime.h>

typedef unsigned short u16;
typedef __attribute__((ext_vector_type(8))) __bf16 bf16x8;
typedef __attribute__((ext_vector_type(4))) float f32x4;

__device__ __forceinline__ float bf2f(u16 u) {
  union { unsigned int i; float f; } v; v.i = ((unsigned int)u) << 16; return v.f;
}
__device__ __forceinline__ u16 f2bf(float f) {
  union { float f; unsigned int i; } v; v.f = f;
  unsigned int u = v.i;
  return (u16)((u + 0x7fffu + ((u >> 16) & 1u)) >> 16);  // RNE
}
__device__ __forceinline__ void async16(void* lds, const void* g) {
  __builtin_amdgcn_global_load_lds(
      (const __attribute__((address_space(1))) unsigned int*)g,
      (__attribute__((address_space(3))) unsigned int*)lds, 16, 0, 0);
}

// ---------------- conversions ----------------
__global__ void k_convert_x(const float* __restrict__ x, u16* __restrict__ xb) {
  int idx = blockIdx.x * 256 + threadIdx.x;       // 65536*512 threads
  int m = idx >> 9, c = idx & 511;
  float v = (c < 500) ? x[(size_t)m * 500 + c] : 0.f;
  xb[idx] = f2bf(v);
}

__global__ void k_convert_w(const float* __restrict__ Wq, const float* __restrict__ Wk,
                            const float* __restrict__ Wv, u16* __restrict__ Wt) {
  int idx = blockIdx.x * 256 + threadIdx.x;       // 3*512*512
  int g = idx >> 18;
  int r = idx & 262143;
  int n = r >> 9, k = r & 511;
  const float* W = (g == 0) ? Wq : (g == 1) ? Wk : Wv;
  float v = (n < 500 && k < 500) ? W[(size_t)k * 500 + n] : 0.f;   // transpose
  Wt[idx] = f2bf(v);
}

__global__ void k_tables(float* __restrict__ cos_t, float* __restrict__ sin_t) {
  int t = blockIdx.x, i = threadIdx.x;
  float c = 0.f, s = 0.f;
  if (i < 250) {
    float ex = (2.0f * (float)(i >> 1)) / 500.0f;
    float fr = powf(1e-4f, ex);
    float ang = (float)t * fr;
    c = cosf(ang); s = sinf(ang);
  }
  cos_t[t * 256 + i] = c;
  sin_t[t * 256 + i] = s;
}

// ---------------- QKV projection GEMM ----------------
// C[m][n] = sum_k xb[m][k] * Wt[n][k]   (Wt is W^T, padded)
// BK=64; LDS tiles [128][64] with 16B-slot XOR swizzle (slot' = slot ^ (row&7)).
// global_load_lds dest stays LINEAR (gi*16); the SOURCE address is pre-swizzled.
__global__ __launch_bounds__(256) void k_gemm_qkv(
    const u16* __restrict__ xb, const u16* __restrict__ Wt,
    u16* __restrict__ qb, u16* __restrict__ kb, u16* __restrict__ vT) {
  __shared__ u16 As[128][64];   // 16KB
  __shared__ u16 Bs[128][64];   // 16KB
  const int tid = threadIdx.x;
  const int lane = tid & 63;
  const int w = tid >> 6;
  const int wm = (w >> 1) * 64, wn = (w & 1) * 64;
  const int bm = blockIdx.x * 128;
  const int bn = blockIdx.y * 128;
  const int g = blockIdx.z;
  const int lrow = lane & 15, lhi = lane >> 4;
  const int sx = lrow & 7;      // read-side XOR term (row&7 == lrow&7 here)

  const u16* Ab = xb + (size_t)bm * 512;
  const u16* Bb = Wt + ((size_t)(g * 512 + bn)) * 512;

  f32x4 acc[4][4] = {};

  for (int k0 = 0; k0 < 512; k0 += 64) {
    __syncthreads();
#pragma unroll
    for (int it = 0; it < 4; ++it) {
      int gi = it * 256 + tid;          // 16B chunk id; LDS byte off = gi*16 (linear)
      int r = gi >> 3;                  // row in tile
      int sl = (gi & 7) ^ (r & 7);      // pre-swizzled logical slot
      async16((char*)As + (size_t)gi * 16, Ab + (size_t)r * 512 + k0 + sl * 8);
      async16((char*)Bs + (size_t)gi * 16, Bb + (size_t)r * 512 + k0 + sl * 8);
    }
    __syncthreads();
#pragma unroll
    for (int kk = 0; kk < 2; ++kk) {
      bf16x8 a[4], b[4];
#pragma unroll
      for (int mi = 0; mi < 4; ++mi)
        a[mi] = *(const bf16x8*)&As[wm + mi * 16 + lrow][((kk * 4 + lhi) ^ sx) * 8];
#pragma unroll
      for (int ni = 0; ni < 4; ++ni)
        b[ni] = *(const bf16x8*)&Bs[wn + ni * 16 + lrow][((kk * 4 + lhi) ^ sx) * 8];
#pragma unroll
      for (int mi = 0; mi < 4; ++mi)
#pragma unroll
        for (int ni = 0; ni < 4; ++ni)
          acc[mi][ni] = __builtin_amdgcn_mfma_f32_16x16x32_bf16(a[mi], b[ni], acc[mi][ni], 0, 0, 0);
    }
  }

#pragma unroll
  for (int mi = 0; mi < 4; ++mi)
#pragma unroll
    for (int ni = 0; ni < 4; ++ni)
#pragma unroll
      for (int j = 0; j < 4; ++j) {
        int m = bm + wm + mi * 16 + lhi * 4 + j;       // C/D: row=(l>>4)*4+j
        int n = bn + wn + ni * 16 + lrow;              //      col=l&15
        u16 h = f2bf(acc[mi][ni][j]);
        if (g == 0)      qb[(size_t)m * 512 + n] = h;
        else if (g == 1) kb[(size_t)m * 512 + n] = h;
        else             vT[(size_t)(m >> 8) * 131072 + (size_t)n * 256 + (m & 255)] = h;
      }
}

// ---------------- RoPE (in place on q,k), 2 elements/thread ----------------
// consecutive i share cos/sin (freqs use i//2); u32 loads are 4B-aligned (250 even)
__global__ void k_rope(u16* __restrict__ qb, u16* __restrict__ kb,
                       const float* __restrict__ cos_t, const float* __restrict__ sin_t) {
  int gid = blockIdx.x * 256 + threadIdx.x;
  int m = gid >> 7;          // 128 threads per row
  int j = gid & 127;
  if (j >= 125) return;
  int t = m & 255;
  float c = cos_t[t * 256 + 2 * j], s = sin_t[t * 256 + 2 * j];
  size_t base = (size_t)m * 512;

  unsigned int* q1p = (unsigned int*)(qb + base + 2 * j);
  unsigned int* q2p = (unsigned int*)(qb + base + 250 + 2 * j);
  unsigned int u1 = *q1p, u2 = *q2p;
  float a0 = bf2f((u16)u1), a1 = bf2f((u16)(u1 >> 16));
  float b0 = bf2f((u16)u2), b1 = bf2f((u16)(u2 >> 16));
  unsigned int r1 = (unsigned int)f2bf(a0 * c - b0 * s) |
                    ((unsigned int)f2bf(a1 * c - b1 * s) << 16);
  unsigned int r2 = (unsigned int)f2bf(a0 * s + b0 * c) |
                    ((unsigned int)f2bf(a1 * s + b1 * c) << 16);
  *q1p = r1; *q2p = r2;

  unsigned int* k1p = (unsigned int*)(kb + base + 2 * j);
  unsigned int* k2p = (unsigned int*)(kb + base + 250 + 2 * j);
  u1 = *k1p; u2 = *k2p;
  a0 = bf2f((u16)u1); a1 = bf2f((u16)(u1 >> 16));
  b0 = bf2f((u16)u2); b1 = bf2f((u16)(u2 >> 16));
  r1 = (unsigned int)f2bf(a0 * c - b0 * s) |
       ((unsigned int)f2bf(a1 * c - b1 * s) << 16);
  r2 = (unsigned int)f2bf(a0 * s + b0 * c) |
       ((unsigned int)f2bf(a1 * s + b1 * c) << 16);
  *k1p = r1; *k2p = r2;
}

// ---------------- fused causal attention ----------------
// block = (q-tile of 64 rows, batch). 4 waves x 16 rows.
// All LDS tiles XOR-swizzled at 16B-slot granularity; sources pre-swizzled.
__global__ __launch_bounds__(256) void k_attn(
    const u16* __restrict__ qb, const u16* __restrict__ kb,
    const u16* __restrict__ vT, float* __restrict__ out) {
  __shared__ u16 smem[32768];          // 64 KB
  u16* Ks = smem;                      // [32][512]  (phase A)
  u16* Ps = smem + 16384;              // [64][256]
  u16* Vs = smem;                      // [512][32]  (phase B, aliases Ks)

  const int tid = threadIdx.x;
  const int lane = tid & 63;
  const int w = tid >> 6;
  const int t0 = blockIdx.x * 64;
  const int b = blockIdx.y;
  const int smax = t0 + 63;
  const int lrow = lane & 15, lhi = lane >> 4;
  const int sx = lrow & 7;

  // Q fragments held in registers: 16 rows/wave, K=512 -> 16 frags
  const u16* qrow = qb + ((size_t)(b * 256 + t0 + w * 16 + lrow)) * 512;
  bf16x8 qf[16];
#pragma unroll
  for (int kk = 0; kk < 16; ++kk)
    qf[kk] = *(const bf16x8*)(qrow + kk * 32 + lhi * 8);

  // ---- phase A: S = Q K^T (64 x 256), causal tile skip ----
  f32x4 sa[16] = {};
#pragma unroll
  for (int st = 0; st < 8; ++st) {
    const int s0 = st * 32;
    if (s0 <= smax) {
      __syncthreads();
#pragma unroll
      for (int it = 0; it < 8; ++it) {
        int gi = it * 256 + tid;
        int r = gi >> 6;                 // K-row 0..31
        int sl = (gi & 63) ^ (r & 7);    // pre-swizzle low 3 slot bits
        async16(Ks + (size_t)gi * 8, kb + ((size_t)(b * 256 + s0 + r)) * 512 + sl * 8);
      }
      __syncthreads();
#pragma unroll
      for (int ni = 0; ni < 2; ++ni)
#pragma unroll
        for (int kk = 0; kk < 16; ++kk) {
          bf16x8 bf = *(const bf16x8*)&Ks[(ni * 16 + lrow) * 512 + ((kk * 4 + lhi) ^ sx) * 8];
          sa[st * 2 + ni] =
              __builtin_amdgcn_mfma_f32_16x16x32_bf16(qf[kk], bf, sa[st * 2 + ni], 0, 0, 0);
        }
    }
  }

  // ---- softmax (rows spread over 16 lanes sharing lane>>4) ----
  const float scale = 0.04472135954999579f;   // 500^-0.5
  float rmax[4] = {-1e30f, -1e30f, -1e30f, -1e30f};
#pragma unroll
  for (int n = 0; n < 16; ++n) {
    int s = n * 16 + lrow;
#pragma unroll
    for (int j = 0; j < 4; ++j) {
      int t = t0 + w * 16 + lhi * 4 + j;
      float v = sa[n][j] * scale;
      if (s > t) v = -1e30f;
      sa[n][j] = v;
      rmax[j] = fmaxf(rmax[j], v);
    }
  }
#pragma unroll
  for (int j = 0; j < 4; ++j)
#pragma unroll
    for (int msk = 1; msk < 16; msk <<= 1)
      rmax[j] = fmaxf(rmax[j], __shfl_xor(rmax[j], msk, 64));
  float rsum[4] = {0.f, 0.f, 0.f, 0.f};
#pragma unroll
  for (int n = 0; n < 16; ++n)
#pragma unroll
    for (int j = 0; j < 4; ++j) {
      float p = __expf(sa[n][j] - rmax[j]);
      sa[n][j] = p;
      rsum[j] += p;
    }
#pragma unroll
  for (int j = 0; j < 4; ++j)
#pragma unroll
    for (int msk = 1; msk < 16; msk <<= 1)
      rsum[j] += __shfl_xor(rsum[j], msk, 64);
  float rinv[4];
#pragma unroll
  for (int j = 0; j < 4; ++j) rinv[j] = 1.0f / rsum[j];

  // write P (bf16) to LDS, swizzled at 16B-slot granularity
#pragma unroll
  for (int n = 0; n < 16; ++n)
#pragma unroll
    for (int j = 0; j < 4; ++j) {
      int s = n * 16 + lrow;
      int trow = w * 16 + lhi * 4 + j;
      int slot = (s >> 3) ^ (trow & 7);
      Ps[trow * 256 + slot * 8 + (s & 7)] = f2bf(sa[n][j] * rinv[j]);
    }

  // ---- phase B: O = P V  (V tiles [512][32] staged in LDS) ----
  f32x4 o[32] = {};
#pragma unroll
  for (int st = 0; st < 8; ++st) {
    const int s0 = st * 32;
    if (s0 <= smax) {
      __syncthreads();
#pragma unroll
      for (int it = 0; it < 8; ++it) {
        int gi = it * 256 + tid;
        int r = gi >> 2;                 // h-row 0..511
        int sl = (gi & 3) ^ (r & 3);     // pre-swizzle 2 slot bits
        async16(Vs + (size_t)gi * 8, vT + (size_t)b * 131072 + (size_t)r * 256 + s0 + sl * 8);
      }
      __syncthreads();
      bf16x8 pf = *(const bf16x8*)&Ps[(w * 16 + lrow) * 256 + (((st * 4) + lhi) ^ sx) * 8];
#pragma unroll
      for (int ni = 0; ni < 32; ++ni) {
        bf16x8 vf = *(const bf16x8*)&Vs[(ni * 16 + lrow) * 32 + ((lhi ^ (lrow & 3)) * 8)];
        o[ni] = __builtin_amdgcn_mfma_f32_16x16x32_bf16(pf, vf, o[ni], 0, 0, 0);
      }
    }
  }

  // ---- epilogue ----
  const int tb = t0 + w * 16;
#pragma unroll
  for (int ni = 0; ni < 32; ++ni) {
    int h = ni * 16 + lrow;
    if (h < 500) {
#pragma unroll
      for (int j = 0; j < 4; ++j) {
        int t = tb + lhi * 4 + j;
        out[((size_t)(b * 256 + t)) * 500 + h] = o[ni][j];
      }
    }
  }
}

extern "C" void kernel_launch(void* const* d_in, const int* in_sizes, int n_in,
                              void* d_out, int out_size, void* d_ws, size_t ws_size,
                              hipStream_t stream) {
  const float* x  = (const float*)d_in[0];
  const float* Wq = (const float*)d_in[1];
  const float* Wk = (const float*)d_in[2];
  const float* Wv = (const float*)d_in[3];
  float* out = (float*)d_out;

  u16* xb = (u16*)d_ws;                 // [65536][512] bf16
  u16* qb = xb + 33554432;              // [65536][512]
  u16* kb = qb + 33554432;              // [65536][512]
  u16* vT = kb + 33554432;              // [256][512][256]
  u16* Wt = vT + 33554432;              // [1536][512]
  float* cos_t = (float*)(Wt + 786432); // [256][256]
  float* sin_t = cos_t + 65536;         // [256][256]

  k_convert_x<<<131072, 256, 0, stream>>>(x, xb);
  k_convert_w<<<3072, 256, 0, stream>>>(Wq, Wk, Wv, Wt);
  k_tables<<<256, 256, 0, stream>>>(cos_t, sin_t);
  k_gemm_qkv<<<dim3(512, 4, 3), 256, 0, stream>>>(xb, Wt, qb, kb, vT);
  k_rope<<<32768, 256, 0, stream>>>(qb, kb, cos_t, sin_t);
  k_attn<<<dim3(4, 256), 256, 0, stream>>>(qb, kb, vT, out);
}

// Round 3
// 478.821 us; speedup vs baseline: 1.1176x; 1.0060x over previous
//
#include <hip/hip_runtime.h>

typedef unsigned short u16;
typedef __attribute__((ext_vector_type(8))) __bf16 bf16x8;
typedef __attribute__((ext_vector_type(4))) float f32x4;

__device__ __forceinline__ float bf2f(u16 u) {
  union { unsigned int i; float f; } v; v.i = ((unsigned int)u) << 16; return v.f;
}
__device__ __forceinline__ u16 f2bf(float f) {
  union { float f; unsigned int i; } v; v.f = f;
  unsigned int u = v.i;
  return (u16)((u + 0x7fffu + ((u >> 16) & 1u)) >> 16);  // RNE
}
__device__ __forceinline__ void async16(void* lds, const void* g) {
  __builtin_amdgcn_global_load_lds(
      (const __attribute__((address_space(1))) unsigned int*)g,
      (__attribute__((address_space(3))) unsigned int*)lds, 16, 0, 0);
}

// ---------------- conversions ----------------
__global__ void k_convert_x(const float* __restrict__ x, u16* __restrict__ xb) {
  int idx = blockIdx.x * 256 + threadIdx.x;       // 65536*512 threads
  int m = idx >> 9, c = idx & 511;
  float v = (c < 500) ? x[(size_t)m * 500 + c] : 0.f;
  xb[idx] = f2bf(v);
}

__global__ void k_convert_w(const float* __restrict__ Wq, const float* __restrict__ Wk,
                            const float* __restrict__ Wv, u16* __restrict__ Wt) {
  int idx = blockIdx.x * 256 + threadIdx.x;       // 3*512*512
  int g = idx >> 18;
  int r = idx & 262143;
  int n = r >> 9, k = r & 511;
  const float* W = (g == 0) ? Wq : (g == 1) ? Wk : Wv;
  float v = (n < 500 && k < 500) ? W[(size_t)k * 500 + n] : 0.f;   // transpose
  Wt[idx] = f2bf(v);
}

__global__ void k_tables(float* __restrict__ cos_t, float* __restrict__ sin_t) {
  int t = blockIdx.x, i = threadIdx.x;
  float c = 0.f, s = 0.f;
  if (i < 250) {
    float ex = (2.0f * (float)(i >> 1)) / 500.0f;
    float fr = powf(1e-4f, ex);
    float ang = (float)t * fr;
    c = cosf(ang); s = sinf(ang);
  }
  cos_t[t * 256 + i] = c;
  sin_t[t * 256 + i] = s;
}

// ---------------- QKV projection GEMM ----------------
// C[m][n] = sum_k xb[m][k] * Wt[n][k]   (Wt is W^T, padded)
// 256x256 tile, BK=32, 8 waves (2M x 4N). 4-slot LDS ring (128 KiB),
// prefetch distance 3, raw s_barrier + counted vmcnt (never 0 in steady
// state). LDS 16B-slot swizzle: phys_slot = log_slot ^ ((row>>1)&3),
// applied on the PRE-SWIZZLED global source (gload_lds dest stays linear)
// and on the ds_read side.
__global__ __launch_bounds__(512, 2) void k_gemm_qkv(
    const u16* __restrict__ xb, const u16* __restrict__ Wt,
    u16* __restrict__ qb, u16* __restrict__ kb, u16* __restrict__ vT) {
  __shared__ u16 As[4][256][32];   // 64 KB
  __shared__ u16 Bs[4][256][32];   // 64 KB
  const int tid = threadIdx.x;
  const int lane = tid & 63;
  const int w = tid >> 6;              // 0..7
  const int wm = w >> 2, wn = w & 3;   // 2 x 4 wave grid
  const int lrow = lane & 15, lhi = lane >> 4;
  const int axor = (lrow >> 1) & 3;

  // XCD-chunked swizzle: 1536 blocks, 192/XCD; same-bm (6 variants) adjacent.
  int bid = blockIdx.x;
  int wk = (bid & 7) * 192 + (bid >> 3);
  int bmi = wk / 6;
  int j = wk - bmi * 6;
  int g = j >> 1, bni = j & 1;
  const int bm = bmi << 8;
  const int bn = bni << 8;

  const u16* Ab = xb + (size_t)bm * 512;
  const u16* Bb = Wt + ((size_t)(g * 512 + bn)) * 512;

  auto STAGE = [&](int kt) {
    int sl = kt & 3;
#pragma unroll
    for (int ld = 0; ld < 2; ++ld) {
      int gi = ld * 512 + tid;          // 16B chunk id, 0..1023
      int r = gi >> 2, c = gi & 3;
      int cs = (c ^ ((r >> 1) & 3)) * 8;  // pre-swizzled source slot
      async16((char*)As + (size_t)sl * 16384 + (size_t)gi * 16,
              Ab + (size_t)r * 512 + kt * 32 + cs);
      async16((char*)Bs + (size_t)sl * 16384 + (size_t)gi * 16,
              Bb + (size_t)r * 512 + kt * 32 + cs);
    }
  };

  f32x4 acc[8][4] = {};

  STAGE(0); STAGE(1); STAGE(2);                    // 12 loads/thread in flight
  asm volatile("s_waitcnt vmcnt(8)" ::: "memory"); // tile 0 complete
  __builtin_amdgcn_s_barrier();
  asm volatile("" ::: "memory");

  for (int t = 0; t < 16; ++t) {
    if (t + 3 < 16) STAGE(t + 3);                  // issue early (T14/T3)
    const u16* Asl = &As[t & 3][0][0];
    const u16* Bsl = &Bs[t & 3][0][0];
    bf16x8 a[8], bb[4];
#pragma unroll
    for (int mi = 0; mi < 8; ++mi)
      a[mi] = *(const bf16x8*)(Asl + (wm * 128 + mi * 16 + lrow) * 32 + (lhi ^ axor) * 8);
#pragma unroll
    for (int ni = 0; ni < 4; ++ni)
      bb[ni] = *(const bf16x8*)(Bsl + (wn * 64 + ni * 16 + lrow) * 32 + (lhi ^ axor) * 8);
    __builtin_amdgcn_s_setprio(1);
#pragma unroll
    for (int mi = 0; mi < 8; ++mi)
#pragma unroll
      for (int ni = 0; ni < 4; ++ni)
        acc[mi][ni] = __builtin_amdgcn_mfma_f32_16x16x32_bf16(a[mi], bb[ni], acc[mi][ni], 0, 0, 0);
    __builtin_amdgcn_s_setprio(0);
    // counted waits: tile t+1 must be resident before next iteration
    if (t + 3 < 16)      asm volatile("s_waitcnt vmcnt(8)" ::: "memory");
    else if (t + 2 < 16) asm volatile("s_waitcnt vmcnt(4)" ::: "memory");
    else if (t + 1 < 16) asm volatile("s_waitcnt vmcnt(0)" ::: "memory");
    if (t < 15) {
      __builtin_amdgcn_s_barrier();
      asm volatile("" ::: "memory");
    }
  }

  // epilogue
#pragma unroll
  for (int mi = 0; mi < 8; ++mi) {
    int m0 = bm + wm * 128 + mi * 16 + lhi * 4;
#pragma unroll
    for (int ni = 0; ni < 4; ++ni) {
      int n = bn + wn * 64 + ni * 16 + lrow;
#pragma unroll
      for (int jj = 0; jj < 4; ++jj) {
        int m = m0 + jj;
        u16 h = f2bf(acc[mi][ni][jj]);
        if (g == 0)      qb[(size_t)m * 512 + n] = h;
        else if (g == 1) kb[(size_t)m * 512 + n] = h;
        else             vT[(size_t)(m >> 8) * 131072 + (size_t)n * 256 + (m & 255)] = h;
      }
    }
  }
}

// ---------------- RoPE (in place on q,k), 2 elements/thread ----------------
__global__ void k_rope(u16* __restrict__ qb, u16* __restrict__ kb,
                       const float* __restrict__ cos_t, const float* __restrict__ sin_t) {
  int gid = blockIdx.x * 256 + threadIdx.x;
  int m = gid >> 7;          // 128 threads per row
  int j = gid & 127;
  if (j >= 125) return;
  int t = m & 255;
  float c = cos_t[t * 256 + 2 * j], s = sin_t[t * 256 + 2 * j];
  size_t base = (size_t)m * 512;

  unsigned int* q1p = (unsigned int*)(qb + base + 2 * j);
  unsigned int* q2p = (unsigned int*)(qb + base + 250 + 2 * j);
  unsigned int u1 = *q1p, u2 = *q2p;
  float a0 = bf2f((u16)u1), a1 = bf2f((u16)(u1 >> 16));
  float b0 = bf2f((u16)u2), b1 = bf2f((u16)(u2 >> 16));
  unsigned int r1 = (unsigned int)f2bf(a0 * c - b0 * s) |
                    ((unsigned int)f2bf(a1 * c - b1 * s) << 16);
  unsigned int r2 = (unsigned int)f2bf(a0 * s + b0 * c) |
                    ((unsigned int)f2bf(a1 * s + b1 * c) << 16);
  *q1p = r1; *q2p = r2;

  unsigned int* k1p = (unsigned int*)(kb + base + 2 * j);
  unsigned int* k2p = (unsigned int*)(kb + base + 250 + 2 * j);
  u1 = *k1p; u2 = *k2p;
  a0 = bf2f((u16)u1); a1 = bf2f((u16)(u1 >> 16));
  b0 = bf2f((u16)u2); b1 = bf2f((u16)(u2 >> 16));
  r1 = (unsigned int)f2bf(a0 * c - b0 * s) |
       ((unsigned int)f2bf(a1 * c - b1 * s) << 16);
  r2 = (unsigned int)f2bf(a0 * s + b0 * c) |
       ((unsigned int)f2bf(a1 * s + b1 * c) << 16);
  *k1p = r1; *k2p = r2;
}

// ---------------- fused causal attention ----------------
// block = (q-tile of 64 rows, batch). 4 waves x 16 rows.
// XCD swizzle: 4 q-tiles of each batch land on one XCD (K/V L2 reuse).
__global__ __launch_bounds__(256) void k_attn(
    const u16* __restrict__ qb, const u16* __restrict__ kb,
    const u16* __restrict__ vT, float* __restrict__ out) {
  __shared__ u16 smem[32768];          // 64 KB
  u16* Ks = smem;                      // [32][512]  (phase A)
  u16* Ps = smem + 16384;              // [64][256]
  u16* Vs = smem;                      // [512][32]  (phase B, aliases Ks)

  const int tid = threadIdx.x;
  const int lane = tid & 63;
  const int w = tid >> 6;
  int bid = blockIdx.x;                // 1024
  int wk = (bid & 7) * 128 + (bid >> 3);
  const int b = wk >> 2;
  const int t0 = (wk & 3) * 64;
  const int smax = t0 + 63;
  const int lrow = lane & 15, lhi = lane >> 4;
  const int sx = lrow & 7;
  const int vxor = (lrow >> 1) & 3;

  // Q fragments held in registers: 16 rows/wave, K=512 -> 16 frags
  const u16* qrow = qb + ((size_t)(b * 256 + t0 + w * 16 + lrow)) * 512;
  bf16x8 qf[16];
#pragma unroll
  for (int kk = 0; kk < 16; ++kk)
    qf[kk] = *(const bf16x8*)(qrow + kk * 32 + lhi * 8);

  // ---- phase A: S = Q K^T (64 x 256), causal tile skip ----
  f32x4 sa[16] = {};
#pragma unroll
  for (int st = 0; st < 8; ++st) {
    const int s0 = st * 32;
    if (s0 <= smax) {
      __syncthreads();
#pragma unroll
      for (int it = 0; it < 8; ++it) {
        int gi = it * 256 + tid;
        int r = gi >> 6;                 // K-row 0..31
        int sl = (gi & 63) ^ (r & 7);    // pre-swizzle low 3 slot bits
        async16(Ks + (size_t)gi * 8, kb + ((size_t)(b * 256 + s0 + r)) * 512 + sl * 8);
      }
      __syncthreads();
      __builtin_amdgcn_s_setprio(1);
#pragma unroll
      for (int ni = 0; ni < 2; ++ni)
#pragma unroll
        for (int kk = 0; kk < 16; ++kk) {
          bf16x8 bf = *(const bf16x8*)&Ks[(ni * 16 + lrow) * 512 + ((kk * 4 + lhi) ^ sx) * 8];
          sa[st * 2 + ni] =
              __builtin_amdgcn_mfma_f32_16x16x32_bf16(qf[kk], bf, sa[st * 2 + ni], 0, 0, 0);
        }
      __builtin_amdgcn_s_setprio(0);
    }
  }

  // ---- softmax (rows spread over 16 lanes sharing lane>>4) ----
  const float scale = 0.04472135954999579f;   // 500^-0.5
  float rmax[4] = {-1e30f, -1e30f, -1e30f, -1e30f};
#pragma unroll
  for (int n = 0; n < 16; ++n) {
    int s = n * 16 + lrow;
#pragma unroll
    for (int j = 0; j < 4; ++j) {
      int t = t0 + w * 16 + lhi * 4 + j;
      float v = sa[n][j] * scale;
      if (s > t) v = -1e30f;
      sa[n][j] = v;
      rmax[j] = fmaxf(rmax[j], v);
    }
  }
#pragma unroll
  for (int j = 0; j < 4; ++j)
#pragma unroll
    for (int msk = 1; msk < 16; msk <<= 1)
      rmax[j] = fmaxf(rmax[j], __shfl_xor(rmax[j], msk, 64));
  float rsum[4] = {0.f, 0.f, 0.f, 0.f};
#pragma unroll
  for (int n = 0; n < 16; ++n)
#pragma unroll
    for (int j = 0; j < 4; ++j) {
      float p = __expf(sa[n][j] - rmax[j]);
      sa[n][j] = p;
      rsum[j] += p;
    }
#pragma unroll
  for (int j = 0; j < 4; ++j)
#pragma unroll
    for (int msk = 1; msk < 16; msk <<= 1)
      rsum[j] += __shfl_xor(rsum[j], msk, 64);
  float rinv[4];
#pragma unroll
  for (int j = 0; j < 4; ++j) rinv[j] = 1.0f / rsum[j];

  // write P (bf16) to LDS, swizzled at 16B-slot granularity
#pragma unroll
  for (int n = 0; n < 16; ++n)
#pragma unroll
    for (int j = 0; j < 4; ++j) {
      int s = n * 16 + lrow;
      int trow = w * 16 + lhi * 4 + j;
      int slot = (s >> 3) ^ (trow & 7);
      Ps[trow * 256 + slot * 8 + (s & 7)] = f2bf(sa[n][j] * rinv[j]);
    }

  // ---- phase B: O = P V  (V tiles [512][32] staged in LDS) ----
  f32x4 o[32] = {};
#pragma unroll
  for (int st = 0; st < 8; ++st) {
    const int s0 = st * 32;
    if (s0 <= smax) {
      __syncthreads();
#pragma unroll
      for (int it = 0; it < 8; ++it) {
        int gi = it * 256 + tid;
        int r = gi >> 2;                 // h-row 0..511
        int sl = (gi & 3) ^ ((r >> 1) & 3);
        async16(Vs + (size_t)gi * 8, vT + (size_t)b * 131072 + (size_t)r * 256 + s0 + sl * 8);
      }
      __syncthreads();
      bf16x8 pf = *(const bf16x8*)&Ps[(w * 16 + lrow) * 256 + (((st * 4) + lhi) ^ sx) * 8];
      __builtin_amdgcn_s_setprio(1);
#pragma unroll
      for (int ni = 0; ni < 32; ++ni) {
        bf16x8 vf = *(const bf16x8*)&Vs[(ni * 16 + lrow) * 32 + ((lhi ^ vxor) * 8)];
        o[ni] = __builtin_amdgcn_mfma_f32_16x16x32_bf16(pf, vf, o[ni], 0, 0, 0);
      }
      __builtin_amdgcn_s_setprio(0);
    }
  }

  // ---- epilogue ----
  const int tb = t0 + w * 16;
#pragma unroll
  for (int ni = 0; ni < 32; ++ni) {
    int h = ni * 16 + lrow;
    if (h < 500) {
#pragma unroll
      for (int j = 0; j < 4; ++j) {
        int t = tb + lhi * 4 + j;
        out[((size_t)(b * 256 + t)) * 500 + h] = o[ni][j];
      }
    }
  }
}

extern "C" void kernel_launch(void* const* d_in, const int* in_sizes, int n_in,
                              void* d_out, int out_size, void* d_ws, size_t ws_size,
                              hipStream_t stream) {
  const float* x  = (const float*)d_in[0];
  const float* Wq = (const float*)d_in[1];
  const float* Wk = (const float*)d_in[2];
  const float* Wv = (const float*)d_in[3];
  float* out = (float*)d_out;

  u16* xb = (u16*)d_ws;                 // [65536][512] bf16
  u16* qb = xb + 33554432;              // [65536][512]
  u16* kb = qb + 33554432;              // [65536][512]
  u16* vT = kb + 33554432;              // [256][512][256]
  u16* Wt = vT + 33554432;              // [1536][512]
  float* cos_t = (float*)(Wt + 786432); // [256][256]
  float* sin_t = cos_t + 65536;         // [256][256]

  k_convert_x<<<131072, 256, 0, stream>>>(x, xb);
  k_convert_w<<<3072, 256, 0, stream>>>(Wq, Wk, Wv, Wt);
  k_tables<<<256, 256, 0, stream>>>(cos_t, sin_t);
  k_gemm_qkv<<<1536, 512, 0, stream>>>(xb, Wt, qb, kb, vT);
  k_rope<<<32768, 256, 0, stream>>>(qb, kb, cos_t, sin_t);
  k_attn<<<1024, 256, 0, stream>>>(qb, kb, vT, out);
}